// Round 2
// baseline (282.700 us; speedup 1.0000x reference)
//
#include <hip/hip_runtime.h>
#include <stdint.h>

typedef int v4i  __attribute__((ext_vector_type(4)));
typedef int v16i __attribute__((ext_vector_type(16)));

#define DIN 1024
#define QMAXF 127.0f

// Weight quant + swizzle into MFMA-fragment-coalesced layout.
// 16B chunk (n, k16) -> slot [((n>>5)*32 + (k16>>1))*64 + (n&31) + 32*(k16&1)]
// so a wave's K-loop fragment load is ONE contiguous 1KB segment.
__global__ __launch_bounds__(256) void quant_w(
    const float* __restrict__ w, char* __restrict__ wq,
    float* __restrict__ wscale)
{
    int wave = threadIdx.x >> 6;
    int lane = threadIdx.x & 63;
    int r = blockIdx.x * 4 + wave;

    const float* src = w + (size_t)r * DIN;

    float4 v[4];
    #pragma unroll
    for (int j = 0; j < 4; j++)
        v[j] = ((const float4*)src)[lane * 4 + j];

    float a = 0.0f;
    #pragma unroll
    for (int j = 0; j < 4; j++)
        a = fmaxf(a, fmaxf(fmaxf(fabsf(v[j].x), fabsf(v[j].y)),
                           fmaxf(fabsf(v[j].z), fabsf(v[j].w))));
    #pragma unroll
    for (int off = 32; off; off >>= 1)
        a = fmaxf(a, __shfl_xor(a, off));
    a = fmaxf(a, 1e-8f);

    float inv = QMAXF / a;
    int pk[4];
    #pragma unroll
    for (int j = 0; j < 4; j++) {
        int q0 = max(-128, min(127, __float2int_rn(v[j].x * inv)));
        int q1 = max(-128, min(127, __float2int_rn(v[j].y * inv)));
        int q2 = max(-128, min(127, __float2int_rn(v[j].z * inv)));
        int q3 = max(-128, min(127, __float2int_rn(v[j].w * inv)));
        pk[j] = (int)((unsigned)(q0 & 255) | ((unsigned)(q1 & 255) << 8) |
                      ((unsigned)(q2 & 255) << 16) | ((unsigned)(q3 & 255) << 24));
    }
    v4i pkv = { pk[0], pk[1], pk[2], pk[3] };

    int nb  = r >> 5;
    int ks  = lane >> 1;
    int sub = (r & 31) + 32 * (lane & 1);
    ((v4i*)wq)[(size_t)(nb * 32 + ks) * 64 + sub] = pkv;

    if (lane == 0) wscale[r] = a / QMAXF;
}

// Per-token activation quant -> int8 A in fragment order (per 64-row tile slab
// of 64KB, chunk slot s = (r>>5)*2048 + (k16>>1)*64 + (k16&1)*32 + (r&31)).
// Coalesced fp32 reads; XOR-swizzled LDS transpose (conflict-free both sides);
// coalesced 16B global writes. Pure memory-bound.
__global__ __launch_bounds__(1024) void quant_x(
    const float* __restrict__ x, char* __restrict__ aq,
    float* __restrict__ xscale)
{
    __shared__ char Ls[65536];

    int m0 = blockIdx.x * 64;
    int w = threadIdx.x >> 6;
    int lane = threadIdx.x & 63;

    for (int i = 0; i < 4; i++) {
        int r = w * 4 + i;
        const float* src = x + (size_t)(m0 + r) * DIN;
        float4 v[4];
        #pragma unroll
        for (int j = 0; j < 4; j++)
            v[j] = ((const float4*)src)[lane + 64 * j];   // lane-stride 16B

        float a = 0.0f;
        #pragma unroll
        for (int j = 0; j < 4; j++)
            a = fmaxf(a, fmaxf(fmaxf(fabsf(v[j].x), fabsf(v[j].y)),
                               fmaxf(fabsf(v[j].z), fabsf(v[j].w))));
        #pragma unroll
        for (int off = 32; off; off >>= 1)
            a = fmaxf(a, __shfl_xor(a, off));
        a = fmaxf(a, 1e-8f);

        float inv = QMAXF / a;
        #pragma unroll
        for (int j = 0; j < 4; j++) {
            int q0 = max(-128, min(127, __float2int_rn(v[j].x * inv)));
            int q1 = max(-128, min(127, __float2int_rn(v[j].y * inv)));
            int q2 = max(-128, min(127, __float2int_rn(v[j].z * inv)));
            int q3 = max(-128, min(127, __float2int_rn(v[j].w * inv)));
            unsigned pk = (unsigned)(q0 & 255) | ((unsigned)(q1 & 255) << 8) |
                          ((unsigned)(q2 & 255) << 16) | ((unsigned)(q3 & 255) << 24);
            int D = lane + 64 * j;          // int8-dword index in row
            int c = D >> 2;                 // k16 chunk
            int s = ((r >> 5) << 11) | ((c >> 1) << 6) | ((c & 1) << 5) | (r & 31);
            int sp = s ^ ((s >> 6) & 7);    // bank-spread swizzle
            *(unsigned*)(Ls + sp * 16 + (D & 3) * 4) = pk;
        }
        if (lane == 0) xscale[m0 + r] = a / QMAXF;
    }
    __syncthreads();

    // cooperative un-swizzled write-out: fully coalesced 16B stores
    v4i* g = (v4i*)(aq + (size_t)blockIdx.x * 65536);
    #pragma unroll
    for (int j = 0; j < 4; j++) {
        int u = threadIdx.x + (j << 10);
        int up = u ^ ((u >> 6) & 7);
        g[u] = *(const v4i*)(Ls + up * 16);
    }
}

// int8 GEMM. Block = 1024 threads (16 waves), processes 2 consecutive 64-row
// tiles with LDS double-buffer. A staged global->LDS via global_load_lds
// (linear fragment order: zero VGPR cost, conflict-free ds_read_b128); stage
// of tile t+1 issued BEFORE the K-loop of tile t (whole-K-loop latency cover,
// barrier drain is a no-op). Epilogue stores of tile t overlap K-loop of t+1.
__global__ __launch_bounds__(1024) void gemm_i8(
    const char* __restrict__ Aq, const char* __restrict__ Bq,
    const float* __restrict__ xscale, const float* __restrict__ wscale,
    const float* __restrict__ bias, float* __restrict__ out, int N)
{
    __shared__ char As[2][65536];
    __shared__ float xs[2][64];

    int w = threadIdx.x >> 6;
    int lane = threadIdx.x & 63;
    int frow = lane & 31;
    int sel  = lane >> 5;
    int wn   = w * 64;

    const char* bp = Bq + ((size_t)(w * 2) * 2048 + (size_t)lane) * 16;
    int tile0 = blockIdx.x * 2;

    // ---- prologue: stage tile0 -> buf0 ----
    {
        const char* slab = Aq + (size_t)tile0 * 65536;
        #pragma unroll
        for (int j = 0; j < 4; j++) {
            int idx = threadIdx.x + (j << 10);
            __builtin_amdgcn_global_load_lds(
                (const __attribute__((address_space(1))) unsigned*)(slab + idx * 16),
                (__attribute__((address_space(3))) unsigned*)(&As[0][idx * 16]),
                16, 0, 0);
        }
        if (threadIdx.x < 64) xs[0][threadIdx.x] = xscale[tile0 * 64 + threadIdx.x];
    }
    __syncthreads();

    #pragma unroll
    for (int t = 0; t < 2; t++) {
        if (t == 0) {
            // issue stage of tile1 -> buf1; stays in flight during K-loop
            const char* slab = Aq + (size_t)(tile0 + 1) * 65536;
            #pragma unroll
            for (int j = 0; j < 4; j++) {
                int idx = threadIdx.x + (j << 10);
                __builtin_amdgcn_global_load_lds(
                    (const __attribute__((address_space(1))) unsigned*)(slab + idx * 16),
                    (__attribute__((address_space(3))) unsigned*)(&As[1][idx * 16]),
                    16, 0, 0);
            }
            if (threadIdx.x < 64) xs[1][threadIdx.x] = xscale[(tile0 + 1) * 64 + threadIdx.x];
        }

        // ---- K loop on buf t ----
        const char* A0 = &As[t][0] + (frow + 32 * sel) * 16;

        v16i acc00 = {}; v16i acc01 = {}; v16i acc10 = {}; v16i acc11 = {};

        v4i b0c = *(const v4i*)(bp);
        v4i b1c = *(const v4i*)(bp + 32768);
        v4i a0c = *(const v4i*)(A0);
        v4i a1c = *(const v4i*)(A0 + 32768);

        #pragma unroll 4
        for (int ks = 0; ks < 32; ks++) {
            v4i a0n, a1n, b0n, b1n;
            if (ks < 31) {
                b0n = *(const v4i*)(bp + (ks + 1) * 1024);
                b1n = *(const v4i*)(bp + (ks + 1) * 1024 + 32768);
                a0n = *(const v4i*)(A0 + (ks + 1) * 1024);
                a1n = *(const v4i*)(A0 + (ks + 1) * 1024 + 32768);
            }
            acc00 = __builtin_amdgcn_mfma_i32_32x32x32_i8(a0c, b0c, acc00, 0, 0, 0);
            acc01 = __builtin_amdgcn_mfma_i32_32x32x32_i8(a0c, b1c, acc01, 0, 0, 0);
            acc10 = __builtin_amdgcn_mfma_i32_32x32x32_i8(a1c, b0c, acc10, 0, 0, 0);
            acc11 = __builtin_amdgcn_mfma_i32_32x32x32_i8(a1c, b1c, acc11, 0, 0, 0);
            b0c = b0n; b1c = b1n; a0c = a0n; a1c = a1n;
        }

        // ---- epilogue: C/D layout col=lane&31, row=(reg&3)+8*(reg>>2)+4*sel ----
        int m0 = (tile0 + t) * 64;
        int n_lane = lane & 31;
        int rquad = 4 * sel;
        v16i accs[2][2] = {{acc00, acc01}, {acc10, acc11}};
        #pragma unroll
        for (int i = 0; i < 2; i++) {
            int mloc = i * 32;
            #pragma unroll
            for (int j = 0; j < 2; j++) {
                int n = wn + j * 32 + n_lane;
                float wsn = wscale[n];
                float bn = bias[n];
                v16i A = accs[i][j];
                #pragma unroll
                for (int r = 0; r < 16; r++) {
                    int ml = mloc + (r & 3) + 8 * (r >> 2) + rquad;
                    __builtin_nontemporal_store(
                        (float)A[r] * xs[t][ml] * wsn + bn,
                        &out[(size_t)(m0 + ml) * N + n]);
                }
            }
        }

        if (t == 0) __syncthreads();   // drains: stage(t1) long done; stores of t0 cheap
    }
}

extern "C" void kernel_launch(void* const* d_in, const int* in_sizes, int n_in,
                              void* d_out, int out_size, void* d_ws, size_t ws_size,
                              hipStream_t stream)
{
    const float* x    = (const float*)d_in[0];
    const float* w    = (const float*)d_in[1];
    const float* bias = (const float*)d_in[2];
    float* out = (float*)d_out;

    int DOUT = in_sizes[2];        // 1024
    int M = in_sizes[0] / DIN;     // 32768

    char* ws   = (char*)d_ws;
    char* wq   = ws;                                    // DOUT*DIN int8
    float* wsc = (float*)(wq + (size_t)DOUT * DIN);     // DOUT f32
    float* xsc = wsc + DOUT;                            // M f32
    char* aq   = (char*)(xsc + M);                      // M*DIN int8 (frag order)

    quant_w<<<DOUT / 4, 256, 0, stream>>>(w, wq, wsc);
    quant_x<<<M / 64, 1024, 0, stream>>>(x, aq, xsc);
    gemm_i8<<<M / 128, 1024, 0, stream>>>(aq, wq, xsc, wsc, bias, out, DOUT);
}

// Round 3
// 269.891 us; speedup vs baseline: 1.0475x; 1.0475x over previous
//
#include <hip/hip_runtime.h>
#include <stdint.h>

typedef int v4i  __attribute__((ext_vector_type(4)));
typedef int v16i __attribute__((ext_vector_type(16)));

#define DIN 1024
#define QMAXF 127.0f

// Weight quant + swizzle into MFMA-fragment-coalesced layout.
// 16B chunk (n, k16) -> slot [((n>>5)*32 + (k16>>1))*64 + (n&31) + 32*(k16&1)]
// so a wave's K-loop fragment load is ONE contiguous 1KB segment.
__global__ __launch_bounds__(256) void quant_w(
    const float* __restrict__ w, char* __restrict__ wq,
    float* __restrict__ wscale)
{
    int wave = threadIdx.x >> 6;
    int lane = threadIdx.x & 63;
    int r = blockIdx.x * 4 + wave;

    const float* src = w + (size_t)r * DIN;

    float4 v[4];
    #pragma unroll
    for (int j = 0; j < 4; j++)
        v[j] = ((const float4*)src)[lane * 4 + j];

    float a = 0.0f;
    #pragma unroll
    for (int j = 0; j < 4; j++)
        a = fmaxf(a, fmaxf(fmaxf(fabsf(v[j].x), fabsf(v[j].y)),
                           fmaxf(fabsf(v[j].z), fabsf(v[j].w))));
    #pragma unroll
    for (int off = 32; off; off >>= 1)
        a = fmaxf(a, __shfl_xor(a, off));
    a = fmaxf(a, 1e-8f);

    float inv = QMAXF / a;
    int pk[4];
    #pragma unroll
    for (int j = 0; j < 4; j++) {
        int q0 = max(-128, min(127, __float2int_rn(v[j].x * inv)));
        int q1 = max(-128, min(127, __float2int_rn(v[j].y * inv)));
        int q2 = max(-128, min(127, __float2int_rn(v[j].z * inv)));
        int q3 = max(-128, min(127, __float2int_rn(v[j].w * inv)));
        pk[j] = (int)((unsigned)(q0 & 255) | ((unsigned)(q1 & 255) << 8) |
                      ((unsigned)(q2 & 255) << 16) | ((unsigned)(q3 & 255) << 24));
    }
    v4i pkv = { pk[0], pk[1], pk[2], pk[3] };

    int nb  = r >> 5;
    int ks  = lane >> 1;
    int sub = (r & 31) + 32 * (lane & 1);
    ((v4i*)wq)[(size_t)(nb * 32 + ks) * 64 + sub] = pkv;

    if (lane == 0) wscale[r] = a / QMAXF;
}

// Fused per-token quant + int8 GEMM.
// Block = 512 threads (8 waves), tile = 32 M-rows x full N=1024.
// __launch_bounds__(512,4) caps regs at 128 -> 2 blocks/CU: one block's
// quant (HBM read) and epilogue (HBM write) overlap the other's K-loop.
// Per wave: 32Mx128N = 4 N-frags of 32x32, acc = 4x v16i = 64 AGPRs.
// A LDS layout: chunk (r, k16) at slot [ (k16>>1)*64 + (k16&1)*32 + (r ^ (k16>>1)) ]
//   - K-loop ds_read_b128: lane slot = ks*64 + sel*32 + (frow^ks): stride-16B
//     contiguous per wave -> conflict-free.
//   - quant ds_write_b32: bank = ((r&7)^(ks&7))*4 + (lane&3) -> 2 lanes/bank = free.
__global__ __launch_bounds__(512, 4) void gemm_i8_fused(
    const float* __restrict__ x, const char* __restrict__ Bq,
    const float* __restrict__ wscale, const float* __restrict__ bias,
    float* __restrict__ out, int N)
{
    __shared__ char As[32 * 1024];
    __shared__ float xs[32];

    int m0 = blockIdx.x * 32;
    int w = threadIdx.x >> 6;      // 0..7
    int lane = threadIdx.x & 63;

    // ---- fused quant phase: 4 rows per wave, coalesced reads ----
    for (int i = 0; i < 4; i++) {
        int r = w * 4 + i;
        const float* src = x + (size_t)(m0 + r) * DIN;
        float4 v[4];
        #pragma unroll
        for (int j = 0; j < 4; j++)
            v[j] = ((const float4*)src)[lane + 64 * j];   // lane-stride 16B

        float a = 0.0f;
        #pragma unroll
        for (int j = 0; j < 4; j++)
            a = fmaxf(a, fmaxf(fmaxf(fabsf(v[j].x), fabsf(v[j].y)),
                               fmaxf(fabsf(v[j].z), fabsf(v[j].w))));
        #pragma unroll
        for (int off = 32; off; off >>= 1)
            a = fmaxf(a, __shfl_xor(a, off));
        a = fmaxf(a, 1e-8f);

        float inv = QMAXF / a;
        #pragma unroll
        for (int j = 0; j < 4; j++) {
            int q0 = max(-128, min(127, __float2int_rn(v[j].x * inv)));
            int q1 = max(-128, min(127, __float2int_rn(v[j].y * inv)));
            int q2 = max(-128, min(127, __float2int_rn(v[j].z * inv)));
            int q3 = max(-128, min(127, __float2int_rn(v[j].w * inv)));
            unsigned pk = (unsigned)(q0 & 255) | ((unsigned)(q1 & 255) << 8) |
                          ((unsigned)(q2 & 255) << 16) | ((unsigned)(q3 & 255) << 24);
            int D  = lane + 64 * j;         // int8-dword index in row
            int c  = D >> 2;                // 16B k-chunk
            int ks = c >> 1;
            int sb = c & 1;
            int slot = ks * 64 + sb * 32 + (r ^ ks);   // r,ks < 32 -> xor < 32
            *(unsigned*)(As + slot * 16 + (D & 3) * 4) = pk;
        }
        if (lane == 0) xs[r] = a / QMAXF;
    }
    __syncthreads();

    // ---- K loop: per wave 4 N-blocks (nb = w*4 .. w*4+3) ----
    int frow = lane & 31;
    int sel  = lane >> 5;
    const char* bp = Bq + (size_t)w * 131072 + (size_t)lane * 16;
    const char* ap = As + sel * 512;

    v16i acc0 = {}; v16i acc1 = {}; v16i acc2 = {}; v16i acc3 = {};

    v4i b0c = *(const v4i*)(bp);
    v4i b1c = *(const v4i*)(bp + 32768);
    v4i b2c = *(const v4i*)(bp + 65536);
    v4i b3c = *(const v4i*)(bp + 98304);
    v4i ac  = *(const v4i*)(ap + frow * 16);

    #pragma unroll 4
    for (int ks = 0; ks < 32; ks++) {
        v4i b0n, b1n, b2n, b3n, an;
        if (ks < 31) {
            const char* bn = bp + (ks + 1) * 1024;
            b0n = *(const v4i*)(bn);
            b1n = *(const v4i*)(bn + 32768);
            b2n = *(const v4i*)(bn + 65536);
            b3n = *(const v4i*)(bn + 98304);
            an  = *(const v4i*)(ap + (ks + 1) * 1024 + ((frow ^ (ks + 1)) * 16));
        }
        acc0 = __builtin_amdgcn_mfma_i32_32x32x32_i8(ac, b0c, acc0, 0, 0, 0);
        acc1 = __builtin_amdgcn_mfma_i32_32x32x32_i8(ac, b1c, acc1, 0, 0, 0);
        acc2 = __builtin_amdgcn_mfma_i32_32x32x32_i8(ac, b2c, acc2, 0, 0, 0);
        acc3 = __builtin_amdgcn_mfma_i32_32x32x32_i8(ac, b3c, acc3, 0, 0, 0);
        b0c = b0n; b1c = b1n; b2c = b2n; b3c = b3n; ac = an;
    }

    // ---- epilogue: C/D layout col=lane&31, row=(reg&3)+8*(reg>>2)+4*sel ----
    int n_lane = lane & 31;
    int rquad = 4 * sel;
    v16i accs[4] = {acc0, acc1, acc2, acc3};
    #pragma unroll
    for (int j = 0; j < 4; j++) {
        int n = w * 128 + j * 32 + n_lane;
        float wsn = wscale[n];
        float bn = bias[n];
        v16i A = accs[j];
        #pragma unroll
        for (int r = 0; r < 16; r++) {
            int ml = (r & 3) + 8 * (r >> 2) + rquad;
            __builtin_nontemporal_store(
                (float)A[r] * xs[ml] * wsn + bn,
                &out[(size_t)(m0 + ml) * N + n]);
        }
    }
}

extern "C" void kernel_launch(void* const* d_in, const int* in_sizes, int n_in,
                              void* d_out, int out_size, void* d_ws, size_t ws_size,
                              hipStream_t stream)
{
    const float* x    = (const float*)d_in[0];
    const float* w    = (const float*)d_in[1];
    const float* bias = (const float*)d_in[2];
    float* out = (float*)d_out;

    int DOUT = in_sizes[2];        // 1024
    int M = in_sizes[0] / DIN;     // 32768

    char* ws   = (char*)d_ws;
    char* wq   = ws;                                    // DOUT*DIN int8
    float* wsc = (float*)(wq + (size_t)DOUT * DIN);     // DOUT f32

    quant_w<<<DOUT / 4, 256, 0, stream>>>(w, wq, wsc);
    gemm_i8_fused<<<M / 32, 512, 0, stream>>>(x, wq, wsc, bias, out, DOUT);
}

// Round 4
// 262.880 us; speedup vs baseline: 1.0754x; 1.0267x over previous
//
#include <hip/hip_runtime.h>
#include <stdint.h>

typedef int v4i  __attribute__((ext_vector_type(4)));
typedef int v16i __attribute__((ext_vector_type(16)));

#define DIN 1024
#define QMAXF 127.0f

__device__ __forceinline__ float amax4(float4 u) {
    return fmaxf(fmaxf(fabsf(u.x), fabsf(u.y)), fmaxf(fabsf(u.z), fabsf(u.w)));
}

__device__ __forceinline__ float wave_max64(float a) {
    #pragma unroll
    for (int off = 32; off; off >>= 1)
        a = fmaxf(a, __shfl_xor(a, off));
    return a;
}

__device__ __forceinline__ unsigned pack4(float4 u, float inv) {
    int q0 = max(-128, min(127, __float2int_rn(u.x * inv)));
    int q1 = max(-128, min(127, __float2int_rn(u.y * inv)));
    int q2 = max(-128, min(127, __float2int_rn(u.z * inv)));
    int q3 = max(-128, min(127, __float2int_rn(u.w * inv)));
    return (unsigned)(q0 & 255) | ((unsigned)(q1 & 255) << 8) |
           ((unsigned)(q2 & 255) << 16) | ((unsigned)(q3 & 255) << 24);
}

// Weight quant + swizzle into MFMA-fragment-coalesced layout.
// 16B chunk (n, k16) -> slot [((n>>5)*32 + (k16>>1))*64 + (n&31) + 32*(k16&1)]
// so a wave's K-loop fragment load is ONE contiguous 1KB segment.
__global__ __launch_bounds__(256) void quant_w(
    const float* __restrict__ w, char* __restrict__ wq,
    float* __restrict__ wscale)
{
    int wave = threadIdx.x >> 6;
    int lane = threadIdx.x & 63;
    int r = blockIdx.x * 4 + wave;

    const float* src = w + (size_t)r * DIN;

    float4 v[4];
    #pragma unroll
    for (int j = 0; j < 4; j++)
        v[j] = ((const float4*)src)[lane * 4 + j];

    float a = 0.0f;
    #pragma unroll
    for (int j = 0; j < 4; j++)
        a = fmaxf(a, amax4(v[j]));
    a = fmaxf(wave_max64(a), 1e-8f);

    float inv = QMAXF / a;
    int pk[4];
    #pragma unroll
    for (int j = 0; j < 4; j++)
        pk[j] = (int)pack4(v[j], inv);
    v4i pkv = { pk[0], pk[1], pk[2], pk[3] };

    int nb  = r >> 5;
    int ks  = lane >> 1;
    int sub = (r & 31) + 32 * (lane & 1);
    ((v4i*)wq)[(size_t)(nb * 32 + ks) * 64 + sub] = pkv;

    if (lane == 0) wscale[r] = a / QMAXF;
}

// Fused per-token quant + int8 GEMM, 2-tile software pipeline.
// Block = 512 threads (8 waves), 2 tiles of TM=64 rows, grid = M/128 = 256
// = exactly 1 block/CU. Per wave: 64M x 128N -> acc 2x4 v16i (128 AGPR);
// __launch_bounds__(512,2) -> 256-reg budget, 2 waves/SIMD.
// Pipeline: quant(t0) -> [K0 with tile1's x-loads + amax + pack interleaved:
// one row-batch of 4 float4 loads issued every 4th iter AFTER that iter's
// B-prefetch (so B-consumption vmcnt never force-drains them; ~2 K-iters
// ~1100cyc of latency cover), consumed 2 rows later; row finalize packs and
// ds-writes As[1]] -> barrier -> epilogue(t0) stores overlap K1 -> K1 ->
// epilogue(t1).
// A LDS layout: chunk (r, c=k16) at slot [c*64 + (r^c)]:
//   - K read (c = 2ks+sel): 32 lanes read a permutation of 32 consecutive
//     16B slots -> conflict-free.
//   - quant write: bank = ((r^c)&7)*4 + (lane&3), 2 lanes/bank -> free.
__global__ __launch_bounds__(512, 2) void gemm_i8_fused(
    const float* __restrict__ x, const char* __restrict__ Bq,
    const float* __restrict__ wscale, const float* __restrict__ bias,
    float* __restrict__ out, int N)
{
    __shared__ char As[2][65536];
    __shared__ float xs[2][64];

    int m0 = blockIdx.x * 128;
    int m1 = m0 + 64;
    int w = threadIdx.x >> 6;      // 0..7
    int lane = threadIdx.x & 63;

    // ---- quant tile0: 8 rows per wave, coalesced 16B-stride reads ----
    for (int i = 0; i < 8; i++) {
        int r = w * 8 + i;
        const float* src = x + (size_t)(m0 + r) * DIN;
        float4 v0 = ((const float4*)src)[lane];
        float4 v1 = ((const float4*)src)[lane + 64];
        float4 v2 = ((const float4*)src)[lane + 128];
        float4 v3 = ((const float4*)src)[lane + 192];
        float a = fmaxf(fmaxf(amax4(v0), amax4(v1)), fmaxf(amax4(v2), amax4(v3)));
        a = fmaxf(wave_max64(a), 1e-8f);
        float inv = QMAXF / a;
        unsigned p0 = pack4(v0, inv), p1 = pack4(v1, inv);
        unsigned p2 = pack4(v2, inv), p3 = pack4(v3, inv);
        int cb = lane >> 2, bsub = (lane & 3) * 4;
        *(unsigned*)(&As[0][((cb     ) * 64 + (r ^ (cb     ))) * 16 + bsub]) = p0;
        *(unsigned*)(&As[0][((cb + 16) * 64 + (r ^ (cb + 16))) * 16 + bsub]) = p1;
        *(unsigned*)(&As[0][((cb + 32) * 64 + (r ^ (cb + 32))) * 16 + bsub]) = p2;
        *(unsigned*)(&As[0][((cb + 48) * 64 + (r ^ (cb + 48))) * 16 + bsub]) = p3;
        if (lane == 0) xs[0][r] = a / QMAXF;
    }

    // ---- preload tile1 rows 0,1 of this wave (consumed in K0 iters 0..7) ----
    const float* x1b = x + (size_t)(m1 + w * 8) * DIN;
    float4 xq0[4], xq1[4];
    #pragma unroll
    for (int j = 0; j < 4; j++) xq0[j] = ((const float4*)x1b)[lane + 64 * j];
    #pragma unroll
    for (int j = 0; j < 4; j++) xq1[j] = ((const float4*)(x1b + DIN))[lane + 64 * j];

    __syncthreads();

    // ---- K0 over As[0], tile1 quant interleaved ----
    int frow = lane & 31;
    int sel  = lane >> 5;
    const char* bp = Bq + (size_t)w * 131072 + (size_t)lane * 16;

    v16i a00 = {}, a01 = {}, a02 = {}, a03 = {};
    v16i a10 = {}, a11 = {}, a12 = {}, a13 = {};

    v4i bC0 = *(const v4i*)(bp);
    v4i bC1 = *(const v4i*)(bp + 32768);
    v4i bC2 = *(const v4i*)(bp + 65536);
    v4i bC3 = *(const v4i*)(bp + 98304);
    int cI = sel;
    v4i aC0 = *(const v4i*)(&As[0][(cI * 64 + (frow        ^ cI)) * 16]);
    v4i aC1 = *(const v4i*)(&As[0][(cI * 64 + ((frow + 32) ^ cI)) * 16]);

    float am = 0.0f;

    #pragma unroll
    for (int ks = 0; ks < 32; ks++) {
        v4i bN0, bN1, bN2, bN3, aN0, aN1;
        if (ks < 31) {
            const char* bn = bp + (ks + 1) * 1024;
            bN0 = *(const v4i*)(bn);
            bN1 = *(const v4i*)(bn + 32768);
            bN2 = *(const v4i*)(bn + 65536);
            bN3 = *(const v4i*)(bn + 98304);
            int cN = 2 * (ks + 1) + sel;
            aN0 = *(const v4i*)(&As[0][(cN * 64 + (frow        ^ cN)) * 16]);
            aN1 = *(const v4i*)(&As[0][(cN * 64 + ((frow + 32) ^ cN)) * 16]);
        }
        // tile1 quant interleave: consume chunk (ks&3) of row (ks>>2)
        {
            const int i = ks >> 2, jj = ks & 3;
            float4 xv = (i & 1) ? xq1[jj] : xq0[jj];
            am = fmaxf(am, amax4(xv));
            if (jj == 3) {
                float a = fmaxf(wave_max64(am), 1e-8f);
                float inv = QMAXF / a;
                int r = w * 8 + i;
                #pragma unroll
                for (int jq = 0; jq < 4; jq++) {
                    float4 u = (i & 1) ? xq1[jq] : xq0[jq];
                    unsigned pk = pack4(u, inv);
                    int c = (lane >> 2) + 16 * jq;
                    *(unsigned*)(&As[1][(c * 64 + (r ^ c)) * 16 + (lane & 3) * 4]) = pk;
                }
                if (lane == 0) xs[1][r] = a / QMAXF;
                am = 0.0f;
                if (i + 2 < 8) {   // issue next row-batch (consumed 8 iters later)
                    const float* rs = x1b + (size_t)(i + 2) * DIN;
                    #pragma unroll
                    for (int jq = 0; jq < 4; jq++) {
                        float4 nv = ((const float4*)rs)[lane + 64 * jq];
                        if (i & 1) xq1[jq] = nv; else xq0[jq] = nv;
                    }
                }
            }
        }
        a00 = __builtin_amdgcn_mfma_i32_32x32x32_i8(aC0, bC0, a00, 0, 0, 0);
        a01 = __builtin_amdgcn_mfma_i32_32x32x32_i8(aC0, bC1, a01, 0, 0, 0);
        a02 = __builtin_amdgcn_mfma_i32_32x32x32_i8(aC0, bC2, a02, 0, 0, 0);
        a03 = __builtin_amdgcn_mfma_i32_32x32x32_i8(aC0, bC3, a03, 0, 0, 0);
        a10 = __builtin_amdgcn_mfma_i32_32x32x32_i8(aC1, bC0, a10, 0, 0, 0);
        a11 = __builtin_amdgcn_mfma_i32_32x32x32_i8(aC1, bC1, a11, 0, 0, 0);
        a12 = __builtin_amdgcn_mfma_i32_32x32x32_i8(aC1, bC2, a12, 0, 0, 0);
        a13 = __builtin_amdgcn_mfma_i32_32x32x32_i8(aC1, bC3, a13, 0, 0, 0);
        bC0 = bN0; bC1 = bN1; bC2 = bN2; bC3 = bN3; aC0 = aN0; aC1 = aN1;
    }

    __syncthreads();   // As[1]/xs[1] complete

    // ---- epilogue tile0 (stores overlap K1 via L2 writeback) ----
    {
        v16i ac[2][4] = {{a00, a01, a02, a03}, {a10, a11, a12, a13}};
        int n_lane = lane & 31;
        #pragma unroll
        for (int mi = 0; mi < 2; mi++) {
            #pragma unroll
            for (int j = 0; j < 4; j++) {
                int n = w * 128 + j * 32 + n_lane;
                float wsn = wscale[n];
                float bn = bias[n];
                #pragma unroll
                for (int r = 0; r < 16; r++) {
                    int ml = 32 * mi + (r & 3) + 8 * (r >> 2) + 4 * sel;
                    __builtin_nontemporal_store(
                        (float)ac[mi][j][r] * xs[0][ml] * wsn + bn,
                        &out[(size_t)(m0 + ml) * N + n]);
                }
            }
        }
    }

    // ---- K1 over As[1] ----
    v16i d00 = {}, d01 = {}, d02 = {}, d03 = {};
    v16i d10 = {}, d11 = {}, d12 = {}, d13 = {};

    bC0 = *(const v4i*)(bp);
    bC1 = *(const v4i*)(bp + 32768);
    bC2 = *(const v4i*)(bp + 65536);
    bC3 = *(const v4i*)(bp + 98304);
    aC0 = *(const v4i*)(&As[1][(cI * 64 + (frow        ^ cI)) * 16]);
    aC1 = *(const v4i*)(&As[1][(cI * 64 + ((frow + 32) ^ cI)) * 16]);

    #pragma unroll 4
    for (int ks = 0; ks < 32; ks++) {
        v4i bN0, bN1, bN2, bN3, aN0, aN1;
        if (ks < 31) {
            const char* bn = bp + (ks + 1) * 1024;
            bN0 = *(const v4i*)(bn);
            bN1 = *(const v4i*)(bn + 32768);
            bN2 = *(const v4i*)(bn + 65536);
            bN3 = *(const v4i*)(bn + 98304);
            int cN = 2 * (ks + 1) + sel;
            aN0 = *(const v4i*)(&As[1][(cN * 64 + (frow        ^ cN)) * 16]);
            aN1 = *(const v4i*)(&As[1][(cN * 64 + ((frow + 32) ^ cN)) * 16]);
        }
        d00 = __builtin_amdgcn_mfma_i32_32x32x32_i8(aC0, bC0, d00, 0, 0, 0);
        d01 = __builtin_amdgcn_mfma_i32_32x32x32_i8(aC0, bC1, d01, 0, 0, 0);
        d02 = __builtin_amdgcn_mfma_i32_32x32x32_i8(aC0, bC2, d02, 0, 0, 0);
        d03 = __builtin_amdgcn_mfma_i32_32x32x32_i8(aC0, bC3, d03, 0, 0, 0);
        d10 = __builtin_amdgcn_mfma_i32_32x32x32_i8(aC1, bC0, d10, 0, 0, 0);
        d11 = __builtin_amdgcn_mfma_i32_32x32x32_i8(aC1, bC1, d11, 0, 0, 0);
        d12 = __builtin_amdgcn_mfma_i32_32x32x32_i8(aC1, bC2, d12, 0, 0, 0);
        d13 = __builtin_amdgcn_mfma_i32_32x32x32_i8(aC1, bC3, d13, 0, 0, 0);
        bC0 = bN0; bC1 = bN1; bC2 = bN2; bC3 = bN3; aC0 = aN0; aC1 = aN1;
    }

    // ---- epilogue tile1 ----
    {
        v16i dc[2][4] = {{d00, d01, d02, d03}, {d10, d11, d12, d13}};
        int n_lane = lane & 31;
        #pragma unroll
        for (int mi = 0; mi < 2; mi++) {
            #pragma unroll
            for (int j = 0; j < 4; j++) {
                int n = w * 128 + j * 32 + n_lane;
                float wsn = wscale[n];
                float bn = bias[n];
                #pragma unroll
                for (int r = 0; r < 16; r++) {
                    int ml = 32 * mi + (r & 3) + 8 * (r >> 2) + 4 * sel;
                    __builtin_nontemporal_store(
                        (float)dc[mi][j][r] * xs[1][ml] * wsn + bn,
                        &out[(size_t)(m1 + ml) * N + n]);
                }
            }
        }
    }
}

extern "C" void kernel_launch(void* const* d_in, const int* in_sizes, int n_in,
                              void* d_out, int out_size, void* d_ws, size_t ws_size,
                              hipStream_t stream)
{
    const float* x    = (const float*)d_in[0];
    const float* w    = (const float*)d_in[1];
    const float* bias = (const float*)d_in[2];
    float* out = (float*)d_out;

    int DOUT = in_sizes[2];        // 1024
    int M = in_sizes[0] / DIN;     // 32768

    char* ws   = (char*)d_ws;
    char* wq   = ws;                                    // DOUT*DIN int8
    float* wsc = (float*)(wq + (size_t)DOUT * DIN);     // DOUT f32

    quant_w<<<DOUT / 4, 256, 0, stream>>>(w, wq, wsc);
    gemm_i8_fused<<<M / 128, 512, 0, stream>>>(x, wq, wsc, bias, out, DOUT);
}